// Round 8
// baseline (851.453 us; speedup 1.0000x reference)
//
#include <hip/hip_runtime.h>

#define S_ 32
#define O_ 64
#define T_ 91
#define C_ 128
#define H_ 8

typedef __attribute__((ext_vector_type(8))) short short8;
typedef __attribute__((ext_vector_type(4))) short short4b;
typedef __attribute__((ext_vector_type(4))) float f32x4;

// Pre-split weights (bf16 hi/lo, MFMA-frag-linear), written by prep_all each call.
__device__ short g_wqa_h[384 * 128], g_wqa_l[384 * 128];
__device__ short g_wqt_h[384 * 128], g_wqt_l[384 * 128];
__device__ short g_wpa_h[128 * 128], g_wpa_l[128 * 128];
__device__ short g_wpt_h[128 * 128], g_wpt_l[128 * 128];

__device__ __forceinline__ void splitf(float f, short& h, short& l) {
    unsigned u = __float_as_uint(f);
    float hf = __uint_as_float(u & 0xffff0000u);
    h = (short)(u >> 16);
    l = (short)(__float_as_uint(f - hf) >> 16);
}

__device__ __forceinline__ void split8g(const float* p, short8& h, short8& l) {
    float4 a = *(const float4*)p;
    float4 b = *(const float4*)(p + 4);
    float v[8] = {a.x, a.y, a.z, a.w, b.x, b.y, b.z, b.w};
    #pragma unroll
    for (int j = 0; j < 8; ++j) { short hh, ll; splitf(v[j], hh, ll); h[j] = hh; l[j] = ll; }
}

__device__ __forceinline__ void split4v(f32x4 v, short4b& h, short4b& l) {
    #pragma unroll
    for (int j = 0; j < 4; ++j) { short hh, ll; splitf(v[j], hh, ll); h[j] = hh; l[j] = ll; }
}

// ---------------------------------------------------------------------------
// Weight prep: all four matrices -> hi/lo bf16, frag-linear:
// element (c,k): ct=c>>4, cl=c&15, kp=k>>5, gg=(k>>3)&3, j=k&7
//   slot = ct*2048 + kp*512 + (cl+16*gg)*8 + j
// ---------------------------------------------------------------------------
__global__ __launch_bounds__(256) void prep_all(
    const float* __restrict__ wqa, const float* __restrict__ wqt,
    const float* __restrict__ wpa, const float* __restrict__ wpt)
{
    int t = blockIdx.x * 256 + threadIdx.x;     // 16384 total
    const float* src; short* dh; short* dl; int idx;
    if (t < 6144)       { src = wqa; dh = g_wqa_h; dl = g_wqa_l; idx = t; }
    else if (t < 12288) { src = wqt; dh = g_wqt_h; dl = g_wqt_l; idx = t - 6144; }
    else if (t < 14336) { src = wpa; dh = g_wpa_h; dl = g_wpa_l; idx = t - 12288; }
    else                { src = wpt; dh = g_wpt_h; dl = g_wpt_l; idx = t - 14336; }
    int c = idx >> 4, gk = idx & 15;
    int kp = gk >> 2, gg = gk & 3;
    int ct = c >> 4, cl = c & 15;
    const float* s = src + (long)c * C_ + gk * 8;
    long slot = (long)ct * 2048 + kp * 512 + (cl + 16 * gg) * 8;
    short8 vh, vl;
    split8g(s, vh, vl);
    *(short8*)(dh + slot) = vh;
    *(short8*)(dl + slot) = vl;
}

// ---------------------------------------------------------------------------
// Fused pass (QKV + masked attention + proj). Block = one batch, 8 waves = heads.
// __launch_bounds__(512,4): force <=128 VGPR+AGPR -> 2 blocks/CU.
// Stage 1 runs in two K-passes (Q,K then V) to halve peak accumulator regs.
// Stage 2 streams sa per key-tile; exp2 via raw v_exp_f32 builtin.
// Stage 3 loads proj weights late (low-pressure window).
// ---------------------------------------------------------------------------
template<int N, int NT, int PASS>
__global__ __launch_bounds__(512, 4) void fused_pass(
    const float* __restrict__ xg, const int* __restrict__ mask,
    const float* __restrict__ bproj, float* __restrict__ yout,
    int bdiv, long bs1, long bs2, long ts, long m1, long m2)
{
    constexpr bool FULL = (NT * 16 == N);
    extern __shared__ char smem[];
    short* xh = (short*)smem;                       // NT*2048 shorts
    short* xl = xh + NT * 2048;                     // NT*2048 shorts
    short* yh = xh;                                 // aliases x region (after sync)
    short* yl = xl;
    int*   s_m = (int*)(smem + NT * 8192);          // NT*16 ints

    const short* Wh = (PASS == 0) ? g_wqa_h : g_wqt_h;
    const short* Wl = (PASS == 0) ? g_wqa_l : g_wqt_l;
    const short* Ph = (PASS == 0) ? g_wpa_h : g_wpt_h;
    const short* Pl = (PASS == 0) ? g_wpa_l : g_wpt_l;

    const int tid = threadIdx.x;
    const int wv = tid >> 6, l = tid & 63;
    const int ic = l & 15, g = l >> 4;
    const int b = blockIdx.x;
    const int s = b / bdiv, u = b - s * bdiv;
    const long xbase = (long)s * bs1 + (long)u * bs2;
    const long mbase = (long)s * (O_ * T_) + (long)u * m1;

    // ---- Stage 0: stage x (split, frag-linear) + mask
    for (int gi = tid; gi < NT * 256; gi += 512) {
        int token = gi >> 4, cg = gi & 15;
        int kp = cg >> 2, gg = cg & 3;
        int slot = ((token >> 4) * 4 + kp) * 512 + (gg * 16 + (token & 15)) * 8;
        short8 vh, vl;
        if (FULL || token < N) {
            split8g(xg + xbase + (long)token * ts + cg * 8, vh, vl);
        } else {
            #pragma unroll
            for (int j = 0; j < 8; ++j) { vh[j] = 0; vl[j] = 0; }
        }
        *(short8*)(xh + slot) = vh;
        *(short8*)(xl + slot) = vl;
    }
    for (int idx = tid; idx < NT * 16; idx += 512)
        s_m[idx] = (idx < N) ? (mask[mbase + (long)idx * m2] != 0) : 0;
    __syncthreads();

    // per-lane key bitmasks: key j = jt*16 + 4g + r -> bit jt*4+r
    unsigned jbits = 0, mbits = 0;
    #pragma unroll
    for (int jt = 0; jt < NT; ++jt)
        #pragma unroll
        for (int r = 0; r < 4; ++r) {
            int j = jt * 16 + 4 * g + r;
            if (j < N) {
                jbits |= 1u << (jt * 4 + r);
                if (s_m[j]) mbits |= 1u << (jt * 4 + r);
            }
        }

    // ---- Stage 1, phase A: Q and K (head h = wv)
    const int h = wv;
    const float QS = 0.25f * 1.44269504088896f;   // fold softmax scale * log2(e) into Q
    short4b qfh[NT], qfl[NT], kfh[NT], kfl[NT];
    {
        f32x4 aQ[NT], aK[NT];
        #pragma unroll
        for (int t2 = 0; t2 < NT; ++t2) {
            aQ[t2] = (f32x4){0.f,0.f,0.f,0.f};
            aK[t2] = (f32x4){0.f,0.f,0.f,0.f};
        }
        #pragma unroll
        for (int kp = 0; kp < 4; ++kp) {
            short8 wqh = *(const short8*)(Wh + (h * 4 + kp) * 512 + l * 8);
            short8 wql = *(const short8*)(Wl + (h * 4 + kp) * 512 + l * 8);
            short8 wkh = *(const short8*)(Wh + ((8 + h) * 4 + kp) * 512 + l * 8);
            short8 wkl = *(const short8*)(Wl + ((8 + h) * 4 + kp) * 512 + l * 8);
            #pragma unroll
            for (int tt = 0; tt < NT; ++tt) {
                short8 xhv = *(const short8*)(xh + (tt * 4 + kp) * 512 + l * 8);
                short8 xlv = *(const short8*)(xl + (tt * 4 + kp) * 512 + l * 8);
                aQ[tt] = __builtin_amdgcn_mfma_f32_16x16x32_bf16(wqh, xhv, aQ[tt], 0, 0, 0);
                aQ[tt] = __builtin_amdgcn_mfma_f32_16x16x32_bf16(wql, xhv, aQ[tt], 0, 0, 0);
                aQ[tt] = __builtin_amdgcn_mfma_f32_16x16x32_bf16(wqh, xlv, aQ[tt], 0, 0, 0);
                aK[tt] = __builtin_amdgcn_mfma_f32_16x16x32_bf16(wkh, xhv, aK[tt], 0, 0, 0);
                aK[tt] = __builtin_amdgcn_mfma_f32_16x16x32_bf16(wkl, xhv, aK[tt], 0, 0, 0);
                aK[tt] = __builtin_amdgcn_mfma_f32_16x16x32_bf16(wkh, xlv, aK[tt], 0, 0, 0);
            }
        }
        #pragma unroll
        for (int t2 = 0; t2 < NT; ++t2) {
            f32x4 qs = aQ[t2] * QS;
            split4v(qs, qfh[t2], qfl[t2]);
            split4v(aK[t2], kfh[t2], kfl[t2]);
        }
    }
    // ---- Stage 1, phase B: V
    short4b vfh[NT], vfl[NT];
    {
        f32x4 aV[NT];
        #pragma unroll
        for (int t2 = 0; t2 < NT; ++t2) aV[t2] = (f32x4){0.f,0.f,0.f,0.f};
        #pragma unroll
        for (int kp = 0; kp < 4; ++kp) {
            short8 wvh = *(const short8*)(Wh + ((16 + h) * 4 + kp) * 512 + l * 8);
            short8 wvl = *(const short8*)(Wl + ((16 + h) * 4 + kp) * 512 + l * 8);
            #pragma unroll
            for (int tt = 0; tt < NT; ++tt) {
                short8 xhv = *(const short8*)(xh + (tt * 4 + kp) * 512 + l * 8);
                short8 xlv = *(const short8*)(xl + (tt * 4 + kp) * 512 + l * 8);
                aV[tt] = __builtin_amdgcn_mfma_f32_16x16x32_bf16(xhv, wvh, aV[tt], 0, 0, 0);
                aV[tt] = __builtin_amdgcn_mfma_f32_16x16x32_bf16(xlv, wvh, aV[tt], 0, 0, 0);
                aV[tt] = __builtin_amdgcn_mfma_f32_16x16x32_bf16(xhv, wvl, aV[tt], 0, 0, 0);
            }
        }
        #pragma unroll
        for (int t2 = 0; t2 < NT; ++t2) split4v(aV[t2], vfh[t2], vfl[t2]);
    }
    __syncthreads();   // x reads done; LDS region becomes y (split bf16)

    // y-slot constants for this wave's columns c = 16*wv + ic
    const int kpw = wv >> 1;
    const int ggw = (2 * wv + (ic >> 3)) & 3;
    const int jw  = ic & 7;

    // ---- Stage 2: attention
    #pragma unroll
    for (int it = 0; it < NT; ++it) {
        const int query = it * 16 + ic;
        const int qm = s_m[query];                   // padded: 0 for query >= N
        const unsigned msel = qm ? mbits : jbits;
        float sum = 0.f;
        short4b ph[NT];
        #pragma unroll
        for (int jt = 0; jt < NT; ++jt) {
            f32x4 sa = (f32x4){0.f,0.f,0.f,0.f};
            sa = __builtin_amdgcn_mfma_f32_16x16x16bf16_1k(kfh[jt], qfh[it], sa, 0, 0, 0);
            sa = __builtin_amdgcn_mfma_f32_16x16x16bf16_1k(kfl[jt], qfh[it], sa, 0, 0, 0);
            sa = __builtin_amdgcn_mfma_f32_16x16x16bf16_1k(kfh[jt], qfl[it], sa, 0, 0, 0);
            #pragma unroll
            for (int r = 0; r < 4; ++r) {
                int bit = (jt << 2) + r;
                float inner = qm ? sa[r] : 0.f;      // dead row: exp2(0)=1 over valid keys
                float xv = ((msel >> bit) & 1u) ? inner : -1e30f;
                float e = __builtin_amdgcn_exp2f(xv);
                sum += e;
                unsigned ue = __float_as_uint(e);    // RNE to bf16
                ue += 0x7fffu + ((ue >> 16) & 1u);
                ph[jt][r] = (short)(ue >> 16);
            }
        }
        sum += __shfl_xor(sum, 16, 64);
        sum += __shfl_xor(sum, 32, 64);
        const float inv = 1.f / sum;

        f32x4 pv = (f32x4){0.f,0.f,0.f,0.f};
        #pragma unroll
        for (int kt = 0; kt < NT; ++kt) {
            pv = __builtin_amdgcn_mfma_f32_16x16x16bf16_1k(ph[kt], vfh[kt], pv, 0, 0, 0);
            pv = __builtin_amdgcn_mfma_f32_16x16x16bf16_1k(ph[kt], vfl[kt], pv, 0, 0, 0);
        }
        #pragma unroll
        for (int r = 0; r < 4; ++r) {
            int rloc = 4 * g + r;
            int row = it * 16 + rloc;
            int iv = __builtin_amdgcn_ds_bpermute(rloc << 2, __float_as_int(inv));
            float yv = pv[r] * __int_as_float(iv);
            short hh = 0, ll = 0;
            if (FULL || row < N) splitf(yv, hh, ll);
            int slot = (it * 4 + kpw) * 512 + (ggw * 16 + rloc) * 8 + jw;
            yh[slot] = hh;
            yl[slot] = ll;
        }
    }
    __syncthreads();   // y complete (split bf16, frag-linear)

    // ---- Stage 3: proj; wave wv owns output cols [16wv, 16wv+16)
    short8 pwh[4], pwl[4];
    #pragma unroll
    for (int kp = 0; kp < 4; ++kp) {
        pwh[kp] = *(const short8*)(Ph + (wv * 4 + kp) * 512 + l * 8);
        pwl[kp] = *(const short8*)(Pl + (wv * 4 + kp) * 512 + l * 8);
    }
    const float bv = bproj[wv * 16 + ic];
    #pragma unroll
    for (int mt = 0; mt < NT; ++mt) {
        f32x4 acc = (f32x4){0.f,0.f,0.f,0.f};
        #pragma unroll
        for (int kp = 0; kp < 4; ++kp) {
            short8 ayh = *(const short8*)(yh + (mt * 4 + kp) * 512 + l * 8);
            short8 ayl = *(const short8*)(yl + (mt * 4 + kp) * 512 + l * 8);
            acc = __builtin_amdgcn_mfma_f32_16x16x32_bf16(ayh, pwh[kp], acc, 0, 0, 0);
            acc = __builtin_amdgcn_mfma_f32_16x16x32_bf16(ayl, pwh[kp], acc, 0, 0, 0);
            acc = __builtin_amdgcn_mfma_f32_16x16x32_bf16(ayh, pwl[kp], acc, 0, 0, 0);
        }
        #pragma unroll
        for (int r = 0; r < 4; ++r) {
            int row = mt * 16 + 4 * g + r;
            if (FULL || row < N)
                yout[((long)b * N + row) * C_ + wv * 16 + ic] = acc[r] + bv;
        }
    }
}

extern "C" void kernel_launch(void* const* d_in, const int* in_sizes, int n_in,
                              void* d_out, int out_size, void* d_ws, size_t ws_size,
                              hipStream_t stream) {
    const float* x       = (const float*)d_in[0];
    const int*   mask    = (const int*)d_in[1];
    const float* Wqkv_a  = (const float*)d_in[2];
    const float* Wproj_a = (const float*)d_in[3];
    const float* bproj_a = (const float*)d_in[4];
    const float* Wqkv_t  = (const float*)d_in[5];
    const float* Wproj_t = (const float*)d_in[6];
    const float* bproj_t = (const float*)d_in[7];
    float* out = (float*)d_out;
    float* xa  = (float*)d_ws;   // pass-1 output, (s,t,o,c) f32, 95.4 MB

    prep_all<<<64, 256, 0, stream>>>(Wqkv_a, Wqkv_t, Wproj_a, Wproj_t);

    // Pass 1: agent attention. batch (s,t), tokens = objects (N=64).
    {
        const size_t lds = 4 * 8192 + 4 * 64;
        fused_pass<O_, 4, 0><<<S_ * T_, 512, lds, stream>>>(
            x, mask, bproj_a, xa,
            T_, (long)O_ * T_ * C_, (long)C_, (long)T_ * C_,
            1L, (long)T_);
    }
    // Pass 2: time attention. batch (s,o), tokens = timesteps (N=91).
    {
        const size_t lds = 6 * 8192 + 6 * 64;
        fused_pass<T_, 6, 1><<<S_ * O_, 512, lds, stream>>>(
            xa, mask, bproj_t, out,
            O_, (long)T_ * O_ * C_, (long)C_, (long)O_ * C_,
            (long)T_, 1L);
    }
}

// Round 9
// 696.973 us; speedup vs baseline: 1.2216x; 1.2216x over previous
//
#include <hip/hip_runtime.h>

#define S_ 32
#define O_ 64
#define T_ 91
#define C_ 128
#define H_ 8

typedef __attribute__((ext_vector_type(8))) short short8;
typedef __attribute__((ext_vector_type(4))) short short4b;
typedef __attribute__((ext_vector_type(4))) float f32x4;

// Pre-split weights (bf16 hi/lo, MFMA-frag-linear), written by prep_all each call.
__device__ short g_wqa_h[384 * 128], g_wqa_l[384 * 128];
__device__ short g_wqt_h[384 * 128], g_wqt_l[384 * 128];
__device__ short g_wpa_h[128 * 128], g_wpa_l[128 * 128];
__device__ short g_wpt_h[128 * 128], g_wpt_l[128 * 128];

__device__ __forceinline__ void splitf(float f, short& h, short& l) {
    unsigned u = __float_as_uint(f);
    float hf = __uint_as_float(u & 0xffff0000u);
    h = (short)(u >> 16);
    l = (short)(__float_as_uint(f - hf) >> 16);
}

__device__ __forceinline__ void split8g(const float* p, short8& h, short8& l) {
    float4 a = *(const float4*)p;
    float4 b = *(const float4*)(p + 4);
    float v[8] = {a.x, a.y, a.z, a.w, b.x, b.y, b.z, b.w};
    #pragma unroll
    for (int j = 0; j < 8; ++j) { short hh, ll; splitf(v[j], hh, ll); h[j] = hh; l[j] = ll; }
}

__device__ __forceinline__ void split4v(f32x4 v, short4b& h, short4b& l) {
    #pragma unroll
    for (int j = 0; j < 4; ++j) { short hh, ll; splitf(v[j], hh, ll); h[j] = hh; l[j] = ll; }
}

// ---------------------------------------------------------------------------
// Weight prep: all four matrices -> hi/lo bf16, frag-linear:
// element (c,k): ct=c>>4, cl=c&15, kp=k>>5, gg=(k>>3)&3, j=k&7
//   slot = ct*2048 + kp*512 + (cl+16*gg)*8 + j
// ---------------------------------------------------------------------------
__global__ __launch_bounds__(256) void prep_all(
    const float* __restrict__ wqa, const float* __restrict__ wqt,
    const float* __restrict__ wpa, const float* __restrict__ wpt)
{
    int t = blockIdx.x * 256 + threadIdx.x;     // 16384 total
    const float* src; short* dh; short* dl; int idx;
    if (t < 6144)       { src = wqa; dh = g_wqa_h; dl = g_wqa_l; idx = t; }
    else if (t < 12288) { src = wqt; dh = g_wqt_h; dl = g_wqt_l; idx = t - 6144; }
    else if (t < 14336) { src = wpa; dh = g_wpa_h; dl = g_wpa_l; idx = t - 12288; }
    else                { src = wpt; dh = g_wpt_h; dl = g_wpt_l; idx = t - 14336; }
    int c = idx >> 4, gk = idx & 15;
    int kp = gk >> 2, gg = gk & 3;
    int ct = c >> 4, cl = c & 15;
    const float* s = src + (long)c * C_ + gk * 8;
    long slot = (long)ct * 2048 + kp * 512 + (cl + 16 * gg) * 8;
    short8 vh, vl;
    split8g(s, vh, vl);
    *(short8*)(dh + slot) = vh;
    *(short8*)(dl + slot) = vl;
}

// ---------------------------------------------------------------------------
// Fused pass (QKV + masked attention + proj). Block = one batch, 4 waves;
// each wave processes TWO heads sequentially (h = wv, wv+4), holding head-A's
// y in registers (split bf16) while head-B runs. 256-thread blocks make the
// occupancy quantum 4 waves: launch_bounds(256,3) -> 3 blocks/CU (12 waves)
// at <=170 VGPR without spills (round-8 lesson: (512,4) forced spills).
// ---------------------------------------------------------------------------
template<int N, int NT, int PASS>
__global__ __launch_bounds__(256, 3) void fused_pass(
    const float* __restrict__ xg, const int* __restrict__ mask,
    const float* __restrict__ bproj, float* __restrict__ yout,
    int bdiv, long bs1, long bs2, long ts, long m1, long m2)
{
    constexpr bool FULL = (NT * 16 == N);
    extern __shared__ char smem[];
    short* xh = (short*)smem;                       // NT*2048 shorts
    short* xl = xh + NT * 2048;                     // NT*2048 shorts
    short* yh = xh;                                 // aliases x region (after sync)
    short* yl = xl;
    int*   s_m = (int*)(smem + NT * 8192);          // NT*16 ints

    const short* Wh = (PASS == 0) ? g_wqa_h : g_wqt_h;
    const short* Wl = (PASS == 0) ? g_wqa_l : g_wqt_l;
    const short* Ph = (PASS == 0) ? g_wpa_h : g_wpt_h;
    const short* Pl = (PASS == 0) ? g_wpa_l : g_wpt_l;

    const int tid = threadIdx.x;
    const int wv = tid >> 6, l = tid & 63;
    const int ic = l & 15, g = l >> 4;
    const int b = blockIdx.x;
    const int s = b / bdiv, u = b - s * bdiv;
    const long xbase = (long)s * bs1 + (long)u * bs2;
    const long mbase = (long)s * (O_ * T_) + (long)u * m1;

    // ---- Stage 0: stage x (split, frag-linear) + mask
    for (int gi = tid; gi < NT * 256; gi += 256) {
        int token = gi >> 4, cg = gi & 15;
        int kp = cg >> 2, gg = cg & 3;
        int slot = ((token >> 4) * 4 + kp) * 512 + (gg * 16 + (token & 15)) * 8;
        short8 vh, vl;
        if (FULL || token < N) {
            split8g(xg + xbase + (long)token * ts + cg * 8, vh, vl);
        } else {
            #pragma unroll
            for (int j = 0; j < 8; ++j) { vh[j] = 0; vl[j] = 0; }
        }
        *(short8*)(xh + slot) = vh;
        *(short8*)(xl + slot) = vl;
    }
    for (int idx = tid; idx < NT * 16; idx += 256)
        s_m[idx] = (idx < N) ? (mask[mbase + (long)idx * m2] != 0) : 0;
    __syncthreads();

    // per-lane key bitmasks: key j = jt*16 + 4g + r -> bit jt*4+r
    unsigned jbits = 0, mbits = 0;
    #pragma unroll
    for (int jt = 0; jt < NT; ++jt)
        #pragma unroll
        for (int r = 0; r < 4; ++r) {
            int j = jt * 16 + 4 * g + r;
            if (j < N) {
                jbits |= 1u << (jt * 4 + r);
                if (s_m[j]) mbits |= 1u << (jt * 4 + r);
            }
        }

    const float QS = 0.25f * 1.44269504088896f;   // softmax scale * log2(e), folded into Q
    short4b y0h[NT], y0l[NT], y1h[NT], y1l[NT];   // per-head y (split bf16) held in regs

    #pragma unroll
    for (int hp = 0; hp < 2; ++hp) {
        const int h = wv + hp * 4;

        // ---- Stage 1, phase A: Q and K
        short4b qfh[NT], qfl[NT], kfh[NT], kfl[NT];
        {
            f32x4 aQ[NT], aK[NT];
            #pragma unroll
            for (int t2 = 0; t2 < NT; ++t2) {
                aQ[t2] = (f32x4){0.f,0.f,0.f,0.f};
                aK[t2] = (f32x4){0.f,0.f,0.f,0.f};
            }
            #pragma unroll
            for (int kp = 0; kp < 4; ++kp) {
                short8 wqh = *(const short8*)(Wh + (h * 4 + kp) * 512 + l * 8);
                short8 wql = *(const short8*)(Wl + (h * 4 + kp) * 512 + l * 8);
                short8 wkh = *(const short8*)(Wh + ((8 + h) * 4 + kp) * 512 + l * 8);
                short8 wkl = *(const short8*)(Wl + ((8 + h) * 4 + kp) * 512 + l * 8);
                #pragma unroll
                for (int tt = 0; tt < NT; ++tt) {
                    short8 xhv = *(const short8*)(xh + (tt * 4 + kp) * 512 + l * 8);
                    short8 xlv = *(const short8*)(xl + (tt * 4 + kp) * 512 + l * 8);
                    aQ[tt] = __builtin_amdgcn_mfma_f32_16x16x32_bf16(wqh, xhv, aQ[tt], 0, 0, 0);
                    aQ[tt] = __builtin_amdgcn_mfma_f32_16x16x32_bf16(wql, xhv, aQ[tt], 0, 0, 0);
                    aQ[tt] = __builtin_amdgcn_mfma_f32_16x16x32_bf16(wqh, xlv, aQ[tt], 0, 0, 0);
                    aK[tt] = __builtin_amdgcn_mfma_f32_16x16x32_bf16(wkh, xhv, aK[tt], 0, 0, 0);
                    aK[tt] = __builtin_amdgcn_mfma_f32_16x16x32_bf16(wkl, xhv, aK[tt], 0, 0, 0);
                    aK[tt] = __builtin_amdgcn_mfma_f32_16x16x32_bf16(wkh, xlv, aK[tt], 0, 0, 0);
                }
            }
            #pragma unroll
            for (int t2 = 0; t2 < NT; ++t2) {
                f32x4 qs = aQ[t2] * QS;
                split4v(qs, qfh[t2], qfl[t2]);
                split4v(aK[t2], kfh[t2], kfl[t2]);
            }
        }
        // ---- Stage 1, phase B: V
        short4b vfh[NT], vfl[NT];
        {
            f32x4 aV[NT];
            #pragma unroll
            for (int t2 = 0; t2 < NT; ++t2) aV[t2] = (f32x4){0.f,0.f,0.f,0.f};
            #pragma unroll
            for (int kp = 0; kp < 4; ++kp) {
                short8 wvh = *(const short8*)(Wh + ((16 + h) * 4 + kp) * 512 + l * 8);
                short8 wvl = *(const short8*)(Wl + ((16 + h) * 4 + kp) * 512 + l * 8);
                #pragma unroll
                for (int tt = 0; tt < NT; ++tt) {
                    short8 xhv = *(const short8*)(xh + (tt * 4 + kp) * 512 + l * 8);
                    short8 xlv = *(const short8*)(xl + (tt * 4 + kp) * 512 + l * 8);
                    aV[tt] = __builtin_amdgcn_mfma_f32_16x16x32_bf16(xhv, wvh, aV[tt], 0, 0, 0);
                    aV[tt] = __builtin_amdgcn_mfma_f32_16x16x32_bf16(xlv, wvh, aV[tt], 0, 0, 0);
                    aV[tt] = __builtin_amdgcn_mfma_f32_16x16x32_bf16(xhv, wvl, aV[tt], 0, 0, 0);
                }
            }
            #pragma unroll
            for (int t2 = 0; t2 < NT; ++t2) split4v(aV[t2], vfh[t2], vfl[t2]);
        }

        // ---- Stage 2: attention; y kept in registers
        #pragma unroll
        for (int it = 0; it < NT; ++it) {
            const int query = it * 16 + ic;
            const int qm = s_m[query];                   // padded: 0 for query >= N
            const unsigned msel = qm ? mbits : jbits;
            float sum = 0.f;
            short4b ph[NT];
            #pragma unroll
            for (int jt = 0; jt < NT; ++jt) {
                f32x4 sa = (f32x4){0.f,0.f,0.f,0.f};
                sa = __builtin_amdgcn_mfma_f32_16x16x16bf16_1k(kfh[jt], qfh[it], sa, 0, 0, 0);
                sa = __builtin_amdgcn_mfma_f32_16x16x16bf16_1k(kfl[jt], qfh[it], sa, 0, 0, 0);
                sa = __builtin_amdgcn_mfma_f32_16x16x16bf16_1k(kfh[jt], qfl[it], sa, 0, 0, 0);
                #pragma unroll
                for (int r = 0; r < 4; ++r) {
                    int bit = (jt << 2) + r;
                    float inner = qm ? sa[r] : 0.f;      // dead row: exp2(0)=1 over valid keys
                    float xv = ((msel >> bit) & 1u) ? inner : -1e30f;
                    float e = __builtin_amdgcn_exp2f(xv);
                    sum += e;
                    unsigned ue = __float_as_uint(e);    // RNE to bf16
                    ue += 0x7fffu + ((ue >> 16) & 1u);
                    ph[jt][r] = (short)(ue >> 16);
                }
            }
            sum += __shfl_xor(sum, 16, 64);
            sum += __shfl_xor(sum, 32, 64);
            const float inv = 1.f / sum;

            // PV with two accumulators (halve the dependent-MFMA chain)
            f32x4 pv0 = (f32x4){0.f,0.f,0.f,0.f};
            f32x4 pv1 = (f32x4){0.f,0.f,0.f,0.f};
            #pragma unroll
            for (int kt = 0; kt < NT; kt += 2) {
                pv0 = __builtin_amdgcn_mfma_f32_16x16x16bf16_1k(ph[kt], vfh[kt], pv0, 0, 0, 0);
                pv0 = __builtin_amdgcn_mfma_f32_16x16x16bf16_1k(ph[kt], vfl[kt], pv0, 0, 0, 0);
                pv1 = __builtin_amdgcn_mfma_f32_16x16x16bf16_1k(ph[kt+1], vfh[kt+1], pv1, 0, 0, 0);
                pv1 = __builtin_amdgcn_mfma_f32_16x16x16bf16_1k(ph[kt+1], vfl[kt+1], pv1, 0, 0, 0);
            }
            f32x4 pv = pv0 + pv1;
            #pragma unroll
            for (int r = 0; r < 4; ++r) {
                int rloc = 4 * g + r;
                int row = it * 16 + rloc;
                int iv = __builtin_amdgcn_ds_bpermute(rloc << 2, __float_as_int(inv));
                float yv = pv[r] * __int_as_float(iv);
                short hh = 0, ll = 0;
                if (FULL || row < N) splitf(yv, hh, ll);
                if (hp == 0) { y0h[it][r] = hh; y0l[it][r] = ll; }
                else         { y1h[it][r] = hh; y1l[it][r] = ll; }
            }
        }
    }
    __syncthreads();   // all waves done reading x; LDS region becomes y

    // ---- write both heads' y (split bf16, frag-linear) to LDS
    #pragma unroll
    for (int hp = 0; hp < 2; ++hp) {
        const int h = wv + hp * 4;
        const int kpw = h >> 1;
        const int ggw = (2 * h + (ic >> 3)) & 3;
        const int jw  = ic & 7;
        #pragma unroll
        for (int it = 0; it < NT; ++it) {
            #pragma unroll
            for (int r = 0; r < 4; ++r) {
                int rloc = 4 * g + r;
                int slot = (it * 4 + kpw) * 512 + (ggw * 16 + rloc) * 8 + jw;
                yh[slot] = (hp == 0) ? y0h[it][r] : y1h[it][r];
                yl[slot] = (hp == 0) ? y0l[it][r] : y1l[it][r];
            }
        }
    }
    __syncthreads();   // y complete

    // ---- Stage 3: proj; wave wv owns output col tiles {wv, wv+4}
    #pragma unroll
    for (int pc = 0; pc < 2; ++pc) {
        const int ct = wv + pc * 4;
        short8 pwh[4], pwl[4];
        #pragma unroll
        for (int kp = 0; kp < 4; ++kp) {
            pwh[kp] = *(const short8*)(Ph + (ct * 4 + kp) * 512 + l * 8);
            pwl[kp] = *(const short8*)(Pl + (ct * 4 + kp) * 512 + l * 8);
        }
        const float bv = bproj[ct * 16 + ic];
        #pragma unroll
        for (int mt = 0; mt < NT; ++mt) {
            f32x4 acc = (f32x4){0.f,0.f,0.f,0.f};
            #pragma unroll
            for (int kp = 0; kp < 4; ++kp) {
                short8 ayh = *(const short8*)(yh + (mt * 4 + kp) * 512 + l * 8);
                short8 ayl = *(const short8*)(yl + (mt * 4 + kp) * 512 + l * 8);
                acc = __builtin_amdgcn_mfma_f32_16x16x32_bf16(ayh, pwh[kp], acc, 0, 0, 0);
                acc = __builtin_amdgcn_mfma_f32_16x16x32_bf16(ayl, pwh[kp], acc, 0, 0, 0);
                acc = __builtin_amdgcn_mfma_f32_16x16x32_bf16(ayh, pwl[kp], acc, 0, 0, 0);
            }
            #pragma unroll
            for (int r = 0; r < 4; ++r) {
                int row = mt * 16 + 4 * g + r;
                if (FULL || row < N)
                    yout[((long)b * N + row) * C_ + ct * 16 + ic] = acc[r] + bv;
            }
        }
    }
}

extern "C" void kernel_launch(void* const* d_in, const int* in_sizes, int n_in,
                              void* d_out, int out_size, void* d_ws, size_t ws_size,
                              hipStream_t stream) {
    const float* x       = (const float*)d_in[0];
    const int*   mask    = (const int*)d_in[1];
    const float* Wqkv_a  = (const float*)d_in[2];
    const float* Wproj_a = (const float*)d_in[3];
    const float* bproj_a = (const float*)d_in[4];
    const float* Wqkv_t  = (const float*)d_in[5];
    const float* Wproj_t = (const float*)d_in[6];
    const float* bproj_t = (const float*)d_in[7];
    float* out = (float*)d_out;
    float* xa  = (float*)d_ws;   // pass-1 output, (s,t,o,c) f32, 95.4 MB

    prep_all<<<64, 256, 0, stream>>>(Wqkv_a, Wqkv_t, Wproj_a, Wproj_t);

    // Pass 1: agent attention. batch (s,t), tokens = objects (N=64).
    {
        const size_t lds = 4 * 8192 + 4 * 64;
        fused_pass<O_, 4, 0><<<S_ * T_, 256, lds, stream>>>(
            x, mask, bproj_a, xa,
            T_, (long)O_ * T_ * C_, (long)C_, (long)T_ * C_,
            1L, (long)T_);
    }
    // Pass 2: time attention. batch (s,o), tokens = timesteps (N=91).
    {
        const size_t lds = 6 * 8192 + 6 * 64;
        fused_pass<T_, 6, 1><<<S_ * O_, 256, lds, stream>>>(
            xa, mask, bproj_t, out,
            O_, (long)T_ * O_ * C_, (long)C_, (long)O_ * C_,
            (long)T_, 1L);
    }
}